// Round 3
// baseline (1626.619 us; speedup 1.0000x reference)
//
#include <hip/hip_runtime.h>
#include <cstdint>
#include <cstddef>

#define BB 8
#define SS 2
#define TT 512
#define CC 2048
#define ND 1024
#define AD 16384
#define NN 256
#define AN 2048
#define NEGV -1e30f
#define NTH 1024   // fwd block threads == number of arc chunks per graph

// ---------------------------------------------------------------------------
// prep: counting sort of arcs by dst (CSR order) into chunk-transposed SoA
//   meta = gidx | dst<<16   (gidx = LDS gather index into dual-copy alpha)
//   w_t  = weight, pxi[p] = pdf (CSR order, for W precompute)
// plus partial-slot tables for the segmented merge:
//   pbeg = excl-scan(npart); padj[j] = pbeg[j] - (rowptr[j] >> LC)
// After the scatter, a two-choice greedy pass assigns each arc to alpha copy0
// (index src, bank src&31) or copy1 (index N + (src ^ ((src>>5)&31))), picking
// per hardware gather group (wave w, slot i == 64 lanes) the copy whose bank
// has the lower load -> near-conflict-free gathers. Value read is identical.
// One block per graph, blockDim.x == N.
// ---------------------------------------------------------------------------
__global__ void prep_kernel(const int* __restrict__ src, const int* __restrict__ dst,
                            const int* __restrict__ pdf, const float* __restrict__ w,
                            unsigned* __restrict__ meta_t, float* __restrict__ w_t,
                            unsigned* __restrict__ pxi,
                            int* __restrict__ pbeg, int* __restrict__ padj,
                            int N, int A, int LC)
{
    __shared__ int cnt[1024];
    __shared__ int pos[1024];
    __shared__ unsigned char gcnt[8192];   // 32 bank counters x up to 256 groups
    const int g = blockIdx.x;
    src += (size_t)g * A; dst += (size_t)g * A; pdf += (size_t)g * A; w += (size_t)g * A;
    meta_t += (size_t)g * A; w_t += (size_t)g * A; pxi += (size_t)g * A;
    pbeg += (size_t)g * (N + 1); padj += (size_t)g * N;
    const int tid = threadIdx.x;
    cnt[tid] = 0;
    __syncthreads();
    for (int a = tid; a < A; a += blockDim.x) atomicAdd(&cnt[dst[a]], 1);
    __syncthreads();
    const int deg = cnt[tid];
    // inclusive scan of deg (Hillis-Steele) -> exclusive row offset r0
    pos[tid] = deg;
    __syncthreads();
    for (int off = 1; off < blockDim.x; off <<= 1) {
        int add = (tid >= off) ? pos[tid - off] : 0;
        __syncthreads();
        pos[tid] += add;
        __syncthreads();
    }
    const int r0 = pos[tid] - deg;
    // partial counts per state and their exclusive scan
    const int np = deg ? (((r0 + deg - 1) >> LC) - (r0 >> LC) + 1) : 0;
    __syncthreads();
    pos[tid] = np;
    __syncthreads();
    for (int off = 1; off < blockDim.x; off <<= 1) {
        int add = (tid >= off) ? pos[tid - off] : 0;
        __syncthreads();
        pos[tid] += add;
        __syncthreads();
    }
    const int pexcl = pos[tid] - np;
    pbeg[tid] = pexcl;
    if (tid == blockDim.x - 1) pbeg[N] = pexcl + np;
    padj[tid] = pexcl - (r0 >> LC);
    // scatter arcs grouped by dst into chunk-transposed SoA (+ CSR-order pdf)
    cnt[tid] = r0;
    __syncthreads();
    for (int a = tid; a < A; a += blockDim.x) {
        const int d2 = dst[a];
        const int p = atomicAdd(&cnt[d2], 1);
        const int l = p >> LC;              // chunk (= owning fwd thread)
        const int i = p & ((1 << LC) - 1);  // position within chunk
        meta_t[(size_t)i * NTH + l] = (unsigned)src[a] | ((unsigned)d2 << 16);
        w_t[(size_t)i * NTH + l] = w[a];
        pxi[p] = (unsigned)pdf[a];          // CSR order == chunk-major (l*CH+i)
    }
    __syncthreads();
    // two-choice greedy per gather group (wave w, slot i): 64 arcs each
    const int CH = 1 << LC;
    const int ngrp = (NTH / 64) * CH;       // A/64
    if (tid < ngrp) {
        unsigned char* cb = &gcnt[tid * 32];
        for (int b = 0; b < 32; ++b) cb[b] = 0;
        const int i = tid & (CH - 1);
        const int w2 = tid >> LC;
        for (int lane = 0; lane < 64; ++lane) {
            const size_t idx = (size_t)i * NTH + (w2 * 64 + lane);
            const unsigned mt = meta_t[idx];
            const unsigned sv = mt & 0xffffu;
            const unsigned alt = sv ^ ((sv >> 5) & 31u);
            const int b0 = (int)(sv & 31u), b1 = (int)(alt & 31u);
            unsigned gx;
            if (cb[b1] < cb[b0]) { cb[b1]++; gx = (unsigned)N + alt; }
            else                 { cb[b0]++; gx = sv; }
            meta_t[idx] = (mt & 0xffff0000u) | gx;
        }
    }
}

// ---------------------------------------------------------------------------
// W production for one time tile (called by standalone tile-0 kernel and by
// the fused kernel's num blocks for tile k+1):
//   unit = (inst, trel); stage llh row in LDS; W[pos] = row[pdf[pos]] in CSR
//   order; coalesced float4 writes. Layout inst-major: W[inst][trel][arc].
// ---------------------------------------------------------------------------
__device__ void wprep_part(int ub, int nb, int t0, int Tt, const float* __restrict__ est,
                           const unsigned* __restrict__ pxi_den,
                           const unsigned* __restrict__ pxi_num,
                           float* __restrict__ Wd, float* __restrict__ Wn,
                           float* row_s)
{
    const int tid = threadIdx.x;
    const int nden = 16 * Tt;
    const int total = nden + 32 * Tt;
    for (int u = ub; u < total; u += nb) {
        __syncthreads();   // previous unit's row_s readers done
        const float* row; const unsigned* pxi; float* out; int nar;
        if (u < nden) {
            const int inst = u / Tt, trel = u - inst * Tt;
            const int s = inst >> 3, b = inst & 7;
            row = est + ((size_t)(b * SS + s) * TT + (t0 + trel)) * CC;
            pxi = pxi_den;
            out = Wd + ((size_t)inst * Tt + trel) * AD;
            nar = AD;
        } else {
            const int v = u - nden;
            const int inst = v / Tt, trel = v - inst * Tt;   // inst = p*16+g
            const int gg = inst & 15, p = inst >> 4;
            const int s = gg >> 3, b = gg & 7;
            const int sp = p ? (1 - s) : s;
            row = est + ((size_t)(b * SS + sp) * TT + (t0 + trel)) * CC;
            pxi = pxi_num + (size_t)gg * AN;
            out = Wn + ((size_t)inst * Tt + trel) * AN;
            nar = AN;
        }
        row_s[tid] = row[tid]; row_s[tid + 1024] = row[tid + 1024];
        __syncthreads();
        const uint4* p4 = (const uint4*)pxi;
        float4* o4 = (float4*)out;
        const int n4 = nar >> 2;
        for (int k = tid; k < n4; k += 1024) {
            const uint4 pp = p4[k];
            o4[k] = make_float4(row_s[pp.x], row_s[pp.y], row_s[pp.z], row_s[pp.w]);
        }
    }
}

__global__ __launch_bounds__(1024) void wprep0_kernel(
    const float* __restrict__ est,
    const unsigned* __restrict__ pxi_den, const unsigned* __restrict__ pxi_num,
    float* __restrict__ Wd, float* __restrict__ Wn, int t0, int Tt)
{
    __shared__ float row_s[CC];
    wprep_part(blockIdx.x, gridDim.x, t0, Tt, est, pxi_den, pxi_num, Wd, Wn, row_s);
}

template<int CH>
__device__ inline void load_w_row(const float* __restrict__ p, float* dst)
{
    if constexpr (CH == 16) {
        const float4* p4 = (const float4*)p;
        const float4 a = p4[0], b = p4[1], c = p4[2], d = p4[3];
        dst[0]=a.x;  dst[1]=a.y;  dst[2]=a.z;  dst[3]=a.w;
        dst[4]=b.x;  dst[5]=b.y;  dst[6]=b.z;  dst[7]=b.w;
        dst[8]=c.x;  dst[9]=c.y;  dst[10]=c.z; dst[11]=c.w;
        dst[12]=d.x; dst[13]=d.y; dst[14]=d.z; dst[15]=d.w;
    } else {
        const float2 v = *(const float2*)p;
        dst[0] = v.x; dst[1] = v.y;
    }
}

// ---------------------------------------------------------------------------
// FSM forward over one time tile [t0, t0+Tt): thread l owns CH consecutive
// (dst-sorted) arcs, records register-resident. alpha kept in LDS in TWO
// copies (copy0 at j, copy1 at N + (j^((j>>5)&31))); each arc's gather index
// (two-choice bank-balanced) is baked into meta. Per step:
//   phase 1: batched independent alpha gathers + per-segment online LSE,
//            packed (m,ss) partials to consecutive LDS slots
//   phase 2: owner merges its <=4 partials (batch-loaded, clamped), writes
//            both alpha copies. Reference semantics preserved exactly.
// alpha persists in global between tiles; final tile does the LSE reduce.
// ---------------------------------------------------------------------------
template<int CH>
__device__ void fsm_forward_tile(int N, int L, int t0, int Tt, bool first, bool last,
    const float* __restrict__ Wrow0, int wstride,
    const unsigned* __restrict__ meta_g, const float* __restrict__ w_g,
    const int* __restrict__ pbeg_g, const int* __restrict__ padj_g,
    const float* __restrict__ initv, const float* __restrict__ finalv,
    float* __restrict__ alpha_gl, float* __restrict__ res,
    float* alpha_s, float2* pk)
{
    const int tid = threadIdx.x;
    // arc records -> registers (coalesced: element i of thread l at i*1024+l)
    unsigned meta[CH]; float wreg[CH];
#pragma unroll
    for (int i = 0; i < CH; ++i) {
        meta[i] = meta_g[i * NTH + tid];
        wreg[i] = w_g[i * NTH + tid];
    }
    unsigned segmask = 0;
#pragma unroll
    for (int i = 0; i < CH; ++i) {
        const int di = (int)(meta[i] >> 16);
        const int dn = (i + 1 < CH) ? (int)(meta[i + 1] >> 16) : -1;
        if (di != dn) segmask |= (1u << i);
    }
    const int slot0 = padj_g[meta[0] >> 16] + tid;  // slots consecutive per thread
    const bool st = tid < N;
    int pb0 = 0, pb1 = 0; float fin = 0.f;
    if (st) {
        const float a0 = first ? initv[tid] : alpha_gl[tid];
        alpha_s[tid] = a0;
        alpha_s[N + (tid ^ ((tid >> 5) & 31))] = a0;   // dual copy (free write)
        pb0 = pbeg_g[tid]; pb1 = pbeg_g[tid + 1];
        fin = finalv[tid];
    }
    int tb = L - t0; if (tb > Tt) tb = Tt; if (tb < 0) tb = 0;
    float wc[CH];
    if (tb > 0) load_w_row<CH>(Wrow0 + (size_t)tid * CH, wc);
    __syncthreads();

    constexpr int G = (CH < 8) ? CH : 8;   // gather/compute group (CH % G == 0)
    for (int trel = 0; trel < tb; ++trel) {
        const bool pre = (trel + 1 < tb);
        float wn[CH];
        if (pre)   // prefetch next step's W; latency hides under phase 1+2
            load_w_row<CH>(Wrow0 + (size_t)(trel + 1) * wstride + (size_t)tid * CH, wn);
        // phase 1: segmented online logsumexp over this thread's chunk
        float m = -INFINITY, ss = 0.f;
        int sl = slot0;
#pragma unroll
        for (int i0 = 0; i0 < CH; i0 += G) {
            float av[G];
#pragma unroll
            for (int gi = 0; gi < G; ++gi)   // independent gathers, batch-issued
                av[gi] = alpha_s[meta[i0 + gi] & 0xffffu];
#pragma unroll
            for (int gi = 0; gi < G; ++gi) {
                const float sc = (av[gi] + wreg[i0 + gi]) + wc[i0 + gi];
                const float d = sc - m;                 // first arc of seg: +inf
                const float e = __expf(-fabsf(d));      // exp(-inf) = 0
                if (d > 0.f) { ss = ss * e + 1.f; m = sc; }
                else         { ss += e; }
                if (segmask & (1u << (i0 + gi))) {      // segment ends here
                    pk[sl] = make_float2(m, ss); ++sl;
                    m = -INFINITY; ss = 0.f;
                }
            }
        }
        __syncthreads();                                 // partials + alpha reads done
        // phase 2: owner merges partials (slot order == arc order), batch-loaded
        if (st) {
            float v2;
            const int cnt = pb1 - pb0;
            if (cnt > 0) {
                const float2 P0 = pk[pb0];
                const float2 P1 = pk[cnt > 1 ? pb0 + 1 : pb0];
                const float2 P2 = pk[cnt > 2 ? pb0 + 2 : pb0];
                const float2 P3 = pk[cnt > 3 ? pb0 + 3 : pb0];
                float mm = P0.x, s2 = P0.y;
                if (cnt > 1) {
                    const float d = P1.x - mm; const float e = __expf(-fabsf(d));
                    if (d > 0.f) { s2 = s2 * e + P1.y; mm = P1.x; } else { s2 += P1.y * e; }
                }
                if (cnt > 2) {
                    const float d = P2.x - mm; const float e = __expf(-fabsf(d));
                    if (d > 0.f) { s2 = s2 * e + P2.y; mm = P2.x; } else { s2 += P2.y * e; }
                }
                if (cnt > 3) {
                    const float d = P3.x - mm; const float e = __expf(-fabsf(d));
                    if (d > 0.f) { s2 = s2 * e + P3.y; mm = P3.x; } else { s2 += P3.y * e; }
                }
                for (int q2 = pb0 + 4; q2 < pb1; ++q2) {  // rare
                    const float2 Pq = pk[q2];
                    const float d = Pq.x - mm; const float e = __expf(-fabsf(d));
                    if (d > 0.f) { s2 = s2 * e + Pq.y; mm = Pq.x; } else { s2 += Pq.y * e; }
                }
                const float mc  = fmaxf(mm, NEGV);
                const float scs = s2 * __expf(mm - mc);
                v2 = mc + __logf(fmaxf(scs, 1e-30f));
            } else {
                v2 = NEGV + __logf(1e-30f);              // no in-arcs (matches ref)
            }
            alpha_s[tid] = v2;
            alpha_s[N + (tid ^ ((tid >> 5) & 31))] = v2;
        }
        __syncthreads();
        if (pre) {
#pragma unroll
            for (int i = 0; i < CH; ++i) wc[i] = wn[i];
        }
    }

    if (last) {
        // logsumexp(alpha + final) over N states, block-wide tree reduce
        const float v = st ? (alpha_s[tid] + fin) : -INFINITY;
        float* red = (float*)pk;
        red[tid] = v;
        __syncthreads();
        for (int off = 512; off > 0; off >>= 1) {
            if (tid < off) red[tid] = fmaxf(red[tid], red[tid + off]);
            __syncthreads();
        }
        const float M = red[0];
        __syncthreads();
        red[tid] = __expf(v - M);
        __syncthreads();
        for (int off = 512; off > 0; off >>= 1) {
            if (tid < off) red[tid] += red[tid + off];
            __syncthreads();
        }
        if (tid == 0) *res = M + __logf(red[0]);
    } else if (st) {
        alpha_gl[tid] = alpha_s[tid];
    }
}

// ---------------------------------------------------------------------------
// fused: blocks 0..15 den fwd (tile k); blocks 16..47 num fwd (tile k) then
// produce W for tile k+1 into the other buffer (hidden under den fwd time).
// Cross-launch stream ordering makes W[k+1] visible to launch k+1.
// ---------------------------------------------------------------------------
__global__ __launch_bounds__(1024) void fused_kernel(
    const int* __restrict__ seqlen,
    const float* __restrict__ Wd, const float* __restrict__ Wn,
    const unsigned* __restrict__ den_meta, const float* __restrict__ den_w,
    const int* __restrict__ den_pbeg, const int* __restrict__ den_padj,
    const float* __restrict__ den_init, const float* __restrict__ den_final,
    const unsigned* __restrict__ num_meta, const float* __restrict__ num_w,
    const int* __restrict__ num_pbeg, const int* __restrict__ num_padj,
    const float* __restrict__ num_init, const float* __restrict__ num_final,
    float* __restrict__ alpha_g, float* __restrict__ res,
    int t0, int Tt, int last,
    const float* __restrict__ est,
    const unsigned* __restrict__ pxi_den, const unsigned* __restrict__ pxi_num,
    float* __restrict__ Wd_next, float* __restrict__ Wn_next)
{
    __shared__ float alpha[2048];   // dual-copy alpha (den: 2*1024)
    __shared__ float2 pk[2048];     // partials; reused as reduce buffer
    __shared__ float row_s[CC];     // wprep staging (num blocks only)
    const int bid = blockIdx.x;
    const bool first = (t0 == 0);
    if (bid < 16) {
        const int s = bid >> 3, b = bid & 7;
        const int L = seqlen[b * SS + s];
        fsm_forward_tile<16>(ND, L, t0, Tt, first, last != 0,
                             Wd + (size_t)bid * Tt * AD, AD,
                             den_meta, den_w, den_pbeg, den_padj,
                             den_init, den_final,
                             alpha_g + (size_t)bid * 1024, &res[bid], alpha, pk);
    } else {
        const int q = bid - 16;
        const int p = q >> 4, g = q & 15;
        const int s = g >> 3, b = g & 7;
        const int sp = p ? (1 - s) : s;
        const int L = seqlen[b * SS + sp];
        fsm_forward_tile<2>(NN, L, t0, Tt, first, last != 0,
                            Wn + (size_t)q * Tt * AN, AN,
                            num_meta + (size_t)g * AN, num_w + (size_t)g * AN,
                            num_pbeg + (size_t)g * (NN + 1), num_padj + (size_t)g * NN,
                            num_init + (size_t)g * NN, num_final + (size_t)g * NN,
                            alpha_g + (size_t)bid * 1024, &res[16 + q], alpha, pk);
        if (!last)   // produce next tile's W while den blocks grind
            wprep_part(q, 32, t0 + Tt, Tt, est, pxi_den, pxi_num,
                       Wd_next, Wn_next, row_s);
    }
}

// res layout: [0..15] den (s*8+b), [16..31] num perm0, [32..47] num perm1
__global__ void finalize_kernel(const float* __restrict__ res, float* __restrict__ out)
{
    if (threadIdx.x == 0 && blockIdx.x == 0) {
        float loss = 0.f;
        for (int b = 0; b < BB; ++b) {
            const float den = res[b] + res[8 + b];
            const float n0  = res[16 + b] + res[16 + 8 + b];
            const float n1  = res[32 + b] + res[32 + 8 + b];
            const float nm  = fminf(n0, n1);
            loss += -(nm - den);
        }
        out[0] = loss;
    }
}

extern "C" void kernel_launch(void* const* d_in, const int* in_sizes, int n_in,
                              void* d_out, int out_size, void* d_ws, size_t ws_size,
                              hipStream_t stream)
{
    const float* est       = (const float*)d_in[0];
    const int*   seqlen    = (const int*)  d_in[1];
    const int*   den_src   = (const int*)  d_in[2];
    const int*   den_dst   = (const int*)  d_in[3];
    const int*   den_pdf   = (const int*)  d_in[4];
    const float* den_w     = (const float*)d_in[5];
    const float* den_init  = (const float*)d_in[6];
    const float* den_final = (const float*)d_in[7];
    const int*   num_src   = (const int*)  d_in[8];
    const int*   num_dst   = (const int*)  d_in[9];
    const int*   num_pdf   = (const int*)  d_in[10];
    const float* num_w     = (const float*)d_in[11];
    const float* num_init  = (const float*)d_in[12];
    const float* num_final = (const float*)d_in[13];

    char* ws = (char*)d_ws;
    unsigned* den_meta = (unsigned*)(ws + 0);        //  65536 -> 65536
    float*    den_wt   = (float*)   (ws + 65536);    //  65536 -> 131072
    unsigned* num_meta = (unsigned*)(ws + 131072);   // 131072 -> 262144
    float*    num_wt   = (float*)   (ws + 262144);   // 131072 -> 393216
    unsigned* den_pxi  = (unsigned*)(ws + 393216);   //  65536 -> 458752
    unsigned* num_pxi  = (unsigned*)(ws + 458752);   // 131072 -> 589824
    int*      den_pbeg = (int*)     (ws + 589824);   //   4100 -> 594176
    int*      num_pbeg = (int*)     (ws + 594176);   //  16448 -> 610816
    int*      den_padj = (int*)     (ws + 610816);   //   4096 -> 614912
    int*      num_padj = (int*)     (ws + 614912);   //  16384 -> 631296
    float*    alpha_g  = (float*)   (ws + 631296);   // 196608 -> 827904
    float*    res      = (float*)   (ws + 827904);   //    192 -> 828416
    const size_t fixed = 828416;

    // W double buffer: per buffer Tt*(16*AD + 32*AN)*4 = Tt*1310720 bytes
    int Tt = 64;
    while (Tt > 4 && fixed + 2ull * (size_t)Tt * 1310720ull > ws_size) Tt >>= 1;
    const size_t wbuf_f = (size_t)Tt * (16 * AD + 32 * AN);
    float* Wd0 = (float*)(ws + fixed);
    float* Wn0 = Wd0 + (size_t)16 * Tt * AD;
    float* Wd1 = Wd0 + wbuf_f;
    float* Wn1 = Wd1 + (size_t)16 * Tt * AD;

    // den: CH=16 (LC=4); num: CH=2 (LC=1)
    prep_kernel<<<1, 1024, 0, stream>>>(den_src, den_dst, den_pdf, den_w,
                                        den_meta, den_wt, den_pxi,
                                        den_pbeg, den_padj, ND, AD, 4);
    prep_kernel<<<16, 256, 0, stream>>>(num_src, num_dst, num_pdf, num_w,
                                        num_meta, num_wt, num_pxi,
                                        num_pbeg, num_padj, NN, AN, 1);

    wprep0_kernel<<<256, 1024, 0, stream>>>(est, den_pxi, num_pxi, Wd0, Wn0, 0, Tt);

    const int nt = TT / Tt;
    for (int k = 0; k < nt; ++k) {
        float* WdC = (k & 1) ? Wd1 : Wd0;
        float* WnC = (k & 1) ? Wn1 : Wn0;
        float* WdN = (k & 1) ? Wd0 : Wd1;
        float* WnN = (k & 1) ? Wn0 : Wn1;
        fused_kernel<<<48, 1024, 0, stream>>>(seqlen, WdC, WnC,
                                              den_meta, den_wt, den_pbeg, den_padj,
                                              den_init, den_final,
                                              num_meta, num_wt, num_pbeg, num_padj,
                                              num_init, num_final,
                                              alpha_g, res, k * Tt, Tt,
                                              (k == nt - 1) ? 1 : 0,
                                              est, den_pxi, num_pxi, WdN, WnN);
    }

    finalize_kernel<<<1, 64, 0, stream>>>(res, (float*)d_out);
}

// Round 4
// 1350.630 us; speedup vs baseline: 1.2043x; 1.2043x over previous
//
#include <hip/hip_runtime.h>
#include <cstdint>
#include <cstddef>

#define BB 8
#define SS 2
#define TT 512
#define CC 2048
#define ND 1024
#define AD 16384
#define NN 256
#define AN 2048
#define NEGV -1e30f
#define NTH 1024   // fwd block threads == number of arc chunks per graph
#define NWG 256    // fused grid: 16 den + 32 num + 208 wprep workers

// ---------------------------------------------------------------------------
// prep: counting sort of arcs by dst (CSR order) into chunk-transposed SoA
//   meta = gidx | dst<<16   (gidx = LDS gather index into dual-copy alpha)
//   w_t  = weight, pxi[p] = pdf (CSR order, for W precompute)
// plus partial-slot tables for the segmented merge:
//   pbeg = excl-scan(npart); padj[j] = pbeg[j] - (rowptr[j] >> LC)
// After the scatter, a two-choice greedy pass assigns each arc to alpha copy0
// (index src, bank src&31) or copy1 (index N + (src ^ ((src>>5)&31))), picking
// per hardware gather group (wave w, slot i == 64 lanes) the copy whose bank
// has the lower load -> near-conflict-free gathers. Value read is identical.
// One block per graph, blockDim.x == N.
// ---------------------------------------------------------------------------
__global__ void prep_kernel(const int* __restrict__ src, const int* __restrict__ dst,
                            const int* __restrict__ pdf, const float* __restrict__ w,
                            unsigned* __restrict__ meta_t, float* __restrict__ w_t,
                            unsigned* __restrict__ pxi,
                            int* __restrict__ pbeg, int* __restrict__ padj,
                            int N, int A, int LC)
{
    __shared__ int cnt[1024];
    __shared__ int pos[1024];
    __shared__ unsigned char gcnt[8192];   // 32 bank counters x up to 256 groups
    const int g = blockIdx.x;
    src += (size_t)g * A; dst += (size_t)g * A; pdf += (size_t)g * A; w += (size_t)g * A;
    meta_t += (size_t)g * A; w_t += (size_t)g * A; pxi += (size_t)g * A;
    pbeg += (size_t)g * (N + 1); padj += (size_t)g * N;
    const int tid = threadIdx.x;
    cnt[tid] = 0;
    __syncthreads();
    for (int a = tid; a < A; a += blockDim.x) atomicAdd(&cnt[dst[a]], 1);
    __syncthreads();
    const int deg = cnt[tid];
    // inclusive scan of deg (Hillis-Steele) -> exclusive row offset r0
    pos[tid] = deg;
    __syncthreads();
    for (int off = 1; off < blockDim.x; off <<= 1) {
        int add = (tid >= off) ? pos[tid - off] : 0;
        __syncthreads();
        pos[tid] += add;
        __syncthreads();
    }
    const int r0 = pos[tid] - deg;
    // partial counts per state and their exclusive scan
    const int np = deg ? (((r0 + deg - 1) >> LC) - (r0 >> LC) + 1) : 0;
    __syncthreads();
    pos[tid] = np;
    __syncthreads();
    for (int off = 1; off < blockDim.x; off <<= 1) {
        int add = (tid >= off) ? pos[tid - off] : 0;
        __syncthreads();
        pos[tid] += add;
        __syncthreads();
    }
    const int pexcl = pos[tid] - np;
    pbeg[tid] = pexcl;
    if (tid == blockDim.x - 1) pbeg[N] = pexcl + np;
    padj[tid] = pexcl - (r0 >> LC);
    // scatter arcs grouped by dst into chunk-transposed SoA (+ CSR-order pdf)
    cnt[tid] = r0;
    __syncthreads();
    for (int a = tid; a < A; a += blockDim.x) {
        const int d2 = dst[a];
        const int p = atomicAdd(&cnt[d2], 1);
        const int l = p >> LC;              // chunk (= owning fwd thread)
        const int i = p & ((1 << LC) - 1);  // position within chunk
        meta_t[(size_t)i * NTH + l] = (unsigned)src[a] | ((unsigned)d2 << 16);
        w_t[(size_t)i * NTH + l] = w[a];
        pxi[p] = (unsigned)pdf[a];          // CSR order == chunk-major (l*CH+i)
    }
    __syncthreads();
    // two-choice greedy per gather group (wave w, slot i): 64 arcs each
    const int CH = 1 << LC;
    const int ngrp = (NTH / 64) * CH;       // A/64
    if (tid < ngrp) {
        unsigned char* cb = &gcnt[tid * 32];
        for (int b = 0; b < 32; ++b) cb[b] = 0;
        const int i = tid & (CH - 1);
        const int w2 = tid >> LC;
        for (int lane = 0; lane < 64; ++lane) {
            const size_t idx = (size_t)i * NTH + (w2 * 64 + lane);
            const unsigned mt = meta_t[idx];
            const unsigned sv = mt & 0xffffu;
            const unsigned alt = sv ^ ((sv >> 5) & 31u);
            const int b0 = (int)(sv & 31u), b1 = (int)(alt & 31u);
            unsigned gx;
            if (cb[b1] < cb[b0]) { cb[b1]++; gx = (unsigned)N + alt; }
            else                 { cb[b0]++; gx = sv; }
            meta_t[idx] = (mt & 0xffff0000u) | gx;
        }
    }
}

// ---------------------------------------------------------------------------
// W production for one time tile (tile-0 standalone kernel + the fused
// kernel's dedicated worker blocks for tile k+1):
//   unit = (inst, trel); stage llh row in LDS; W[pos] = row[pdf[pos]] in CSR
//   order; coalesced float4 writes. Layout inst-major: W[inst][trel][arc].
// ---------------------------------------------------------------------------
__device__ void wprep_part(int ub, int nb, int t0, int Tt, const float* __restrict__ est,
                           const unsigned* __restrict__ pxi_den,
                           const unsigned* __restrict__ pxi_num,
                           float* __restrict__ Wd, float* __restrict__ Wn,
                           float* row_s)
{
    const int tid = threadIdx.x;
    const int nden = 16 * Tt;
    const int total = nden + 32 * Tt;
    for (int u = ub; u < total; u += nb) {
        __syncthreads();   // previous unit's row_s readers done
        const float* row; const unsigned* pxi; float* out; int nar;
        if (u < nden) {
            const int inst = u / Tt, trel = u - inst * Tt;
            const int s = inst >> 3, b = inst & 7;
            row = est + ((size_t)(b * SS + s) * TT + (t0 + trel)) * CC;
            pxi = pxi_den;
            out = Wd + ((size_t)inst * Tt + trel) * AD;
            nar = AD;
        } else {
            const int v = u - nden;
            const int inst = v / Tt, trel = v - inst * Tt;   // inst = p*16+g
            const int gg = inst & 15, p = inst >> 4;
            const int s = gg >> 3, b = gg & 7;
            const int sp = p ? (1 - s) : s;
            row = est + ((size_t)(b * SS + sp) * TT + (t0 + trel)) * CC;
            pxi = pxi_num + (size_t)gg * AN;
            out = Wn + ((size_t)inst * Tt + trel) * AN;
            nar = AN;
        }
        row_s[tid] = row[tid]; row_s[tid + 1024] = row[tid + 1024];
        __syncthreads();
        const uint4* p4 = (const uint4*)pxi;
        float4* o4 = (float4*)out;
        const int n4 = nar >> 2;
        for (int k = tid; k < n4; k += 1024) {
            const uint4 pp = p4[k];
            o4[k] = make_float4(row_s[pp.x], row_s[pp.y], row_s[pp.z], row_s[pp.w]);
        }
    }
}

__global__ __launch_bounds__(1024) void wprep0_kernel(
    const float* __restrict__ est,
    const unsigned* __restrict__ pxi_den, const unsigned* __restrict__ pxi_num,
    float* __restrict__ Wd, float* __restrict__ Wn, int t0, int Tt)
{
    __shared__ float row_s[CC];
    wprep_part(blockIdx.x, gridDim.x, t0, Tt, est, pxi_den, pxi_num, Wd, Wn, row_s);
}

template<int CH>
__device__ inline void load_w_row(const float* __restrict__ p, float* dst)
{
    if constexpr (CH == 16) {
        const float4* p4 = (const float4*)p;
        const float4 a = p4[0], b = p4[1], c = p4[2], d = p4[3];
        dst[0]=a.x;  dst[1]=a.y;  dst[2]=a.z;  dst[3]=a.w;
        dst[4]=b.x;  dst[5]=b.y;  dst[6]=b.z;  dst[7]=b.w;
        dst[8]=c.x;  dst[9]=c.y;  dst[10]=c.z; dst[11]=c.w;
        dst[12]=d.x; dst[13]=d.y; dst[14]=d.z; dst[15]=d.w;
    } else {
        const float2 v = *(const float2*)p;
        dst[0] = v.x; dst[1] = v.y;
    }
}

// ---------------------------------------------------------------------------
// FSM forward over one time tile [t0, t0+Tt): thread l owns CH consecutive
// (dst-sorted) arcs, records register-resident. alpha kept in LDS in TWO
// copies (copy0 at j, copy1 at N + (j^((j>>5)&31))); each arc's gather index
// (two-choice bank-balanced) is baked into meta. Per step:
//   phase 1: all CH alpha gathers issued back-to-back, then per-segment
//            online LSE, packed (m,ss) partials to consecutive LDS slots
//   phase 2: owner merges its <=4 partials (batch-loaded, clamped), writes
//            both alpha copies. Reference semantics preserved exactly:
//              sc=(alpha+w)+llh; mc=max(m,NEG); s'=ss*exp(m-mc);
//              new=mc+log(max(s',1e-30))
// alpha persists in global between tiles; final tile does the LSE reduce.
// ---------------------------------------------------------------------------
template<int CH>
__device__ void fsm_forward_tile(int N, int L, int t0, int Tt, bool first, bool last,
    const float* __restrict__ Wrow0, int wstride,
    const unsigned* __restrict__ meta_g, const float* __restrict__ w_g,
    const int* __restrict__ pbeg_g, const int* __restrict__ padj_g,
    const float* __restrict__ initv, const float* __restrict__ finalv,
    float* __restrict__ alpha_gl, float* __restrict__ res,
    float* alpha_s, float2* pk)
{
    const int tid = threadIdx.x;
    // arc records -> registers (coalesced: element i of thread l at i*1024+l)
    unsigned meta[CH]; float wreg[CH];
#pragma unroll
    for (int i = 0; i < CH; ++i) {
        meta[i] = meta_g[i * NTH + tid];
        wreg[i] = w_g[i * NTH + tid];
    }
    unsigned segmask = 0;
#pragma unroll
    for (int i = 0; i < CH; ++i) {
        const int di = (int)(meta[i] >> 16);
        const int dn = (i + 1 < CH) ? (int)(meta[i + 1] >> 16) : -1;
        if (di != dn) segmask |= (1u << i);
    }
    const int slot0 = padj_g[meta[0] >> 16] + tid;  // slots consecutive per thread
    const bool st = tid < N;
    int pb0 = 0, pb1 = 0; float fin = 0.f;
    if (st) {
        const float a0 = first ? initv[tid] : alpha_gl[tid];
        alpha_s[tid] = a0;
        alpha_s[N + (tid ^ ((tid >> 5) & 31))] = a0;   // dual copy (free write)
        pb0 = pbeg_g[tid]; pb1 = pbeg_g[tid + 1];
        fin = finalv[tid];
    }
    int tb = L - t0; if (tb > Tt) tb = Tt; if (tb < 0) tb = 0;
    float wc[CH];
    if (tb > 0) load_w_row<CH>(Wrow0 + (size_t)tid * CH, wc);
    __syncthreads();

    for (int trel = 0; trel < tb; ++trel) {
        const bool pre = (trel + 1 < tb);
        float wn[CH];
        if (pre)   // prefetch next step's W; latency hides under phase 1+2
            load_w_row<CH>(Wrow0 + (size_t)(trel + 1) * wstride + (size_t)tid * CH, wn);
        // phase 1: issue ALL gathers back-to-back, then segmented online LSE
        float av[CH];
#pragma unroll
        for (int i = 0; i < CH; ++i)
            av[i] = alpha_s[meta[i] & 0xffffu];
        float m = -INFINITY, ss = 0.f;
        int sl = slot0;
#pragma unroll
        for (int i = 0; i < CH; ++i) {
            const float sc = (av[i] + wreg[i]) + wc[i];
            const float d = sc - m;                 // first arc of seg: +inf
            const float e = __expf(-fabsf(d));      // exp(-inf) = 0
            if (d > 0.f) { ss = ss * e + 1.f; m = sc; }
            else         { ss += e; }
            if (segmask & (1u << i)) {              // segment ends here
                pk[sl] = make_float2(m, ss); ++sl;
                m = -INFINITY; ss = 0.f;
            }
        }
        __syncthreads();                                 // partials + alpha reads done
        // phase 2: owner merges partials (slot order == arc order), batch-loaded
        if (st) {
            float v2;
            const int cnt = pb1 - pb0;
            if (cnt > 0) {
                const float2 P0 = pk[pb0];
                const float2 P1 = pk[cnt > 1 ? pb0 + 1 : pb0];
                const float2 P2 = pk[cnt > 2 ? pb0 + 2 : pb0];
                const float2 P3 = pk[cnt > 3 ? pb0 + 3 : pb0];
                float mm = P0.x, s2 = P0.y;
                if (cnt > 1) {
                    const float d = P1.x - mm; const float e = __expf(-fabsf(d));
                    if (d > 0.f) { s2 = s2 * e + P1.y; mm = P1.x; } else { s2 += P1.y * e; }
                }
                if (cnt > 2) {
                    const float d = P2.x - mm; const float e = __expf(-fabsf(d));
                    if (d > 0.f) { s2 = s2 * e + P2.y; mm = P2.x; } else { s2 += P2.y * e; }
                }
                if (cnt > 3) {
                    const float d = P3.x - mm; const float e = __expf(-fabsf(d));
                    if (d > 0.f) { s2 = s2 * e + P3.y; mm = P3.x; } else { s2 += P3.y * e; }
                }
                for (int q2 = pb0 + 4; q2 < pb1; ++q2) {  // rare
                    const float2 Pq = pk[q2];
                    const float d = Pq.x - mm; const float e = __expf(-fabsf(d));
                    if (d > 0.f) { s2 = s2 * e + Pq.y; mm = Pq.x; } else { s2 += Pq.y * e; }
                }
                const float mc  = fmaxf(mm, NEGV);
                const float scs = s2 * __expf(mm - mc);
                v2 = mc + __logf(fmaxf(scs, 1e-30f));
            } else {
                v2 = NEGV + __logf(1e-30f);              // no in-arcs (matches ref)
            }
            alpha_s[tid] = v2;
            alpha_s[N + (tid ^ ((tid >> 5) & 31))] = v2;
        }
        __syncthreads();
        if (pre) {
#pragma unroll
            for (int i = 0; i < CH; ++i) wc[i] = wn[i];
        }
    }

    if (last) {
        // logsumexp(alpha + final) over N states, block-wide tree reduce
        const float v = st ? (alpha_s[tid] + fin) : -INFINITY;
        float* red = (float*)pk;
        red[tid] = v;
        __syncthreads();
        for (int off = 512; off > 0; off >>= 1) {
            if (tid < off) red[tid] = fmaxf(red[tid], red[tid + off]);
            __syncthreads();
        }
        const float M = red[0];
        __syncthreads();
        red[tid] = __expf(v - M);
        __syncthreads();
        for (int off = 512; off > 0; off >>= 1) {
            if (tid < off) red[tid] += red[tid + off];
            __syncthreads();
        }
        if (tid == 0) *res = M + __logf(red[0]);
    } else if (st) {
        alpha_gl[tid] = alpha_s[tid];
    }
}

// ---------------------------------------------------------------------------
// fused (grid NWG=256): blocks 0..15 den fwd (tile k); 16..47 num fwd (tile
// k); 48..255 produce W for tile k+1 across 208 CUs (hidden under den time).
// Cross-launch stream ordering makes W[k+1] visible to launch k+1.
// ---------------------------------------------------------------------------
__global__ __launch_bounds__(1024) void fused_kernel(
    const int* __restrict__ seqlen,
    const float* __restrict__ Wd, const float* __restrict__ Wn,
    const unsigned* __restrict__ den_meta, const float* __restrict__ den_w,
    const int* __restrict__ den_pbeg, const int* __restrict__ den_padj,
    const float* __restrict__ den_init, const float* __restrict__ den_final,
    const unsigned* __restrict__ num_meta, const float* __restrict__ num_w,
    const int* __restrict__ num_pbeg, const int* __restrict__ num_padj,
    const float* __restrict__ num_init, const float* __restrict__ num_final,
    float* __restrict__ alpha_g, float* __restrict__ res,
    int t0, int Tt, int last,
    const float* __restrict__ est,
    const unsigned* __restrict__ pxi_den, const unsigned* __restrict__ pxi_num,
    float* __restrict__ Wd_next, float* __restrict__ Wn_next)
{
    __shared__ float alpha[2048];   // dual-copy alpha (den: 2*1024)
    __shared__ float2 pk[2048];     // partials; reused as reduce buffer
    __shared__ float row_s[CC];     // wprep staging (worker blocks only)
    const int bid = blockIdx.x;
    const bool first = (t0 == 0);
    if (bid >= 48) {
        if (!last)   // produce next tile's W, spread over 208 CUs
            wprep_part(bid - 48, NWG - 48, t0 + Tt, Tt, est, pxi_den, pxi_num,
                       Wd_next, Wn_next, row_s);
        return;
    }
    if (bid < 16) {
        const int s = bid >> 3, b = bid & 7;
        const int L = seqlen[b * SS + s];
        fsm_forward_tile<16>(ND, L, t0, Tt, first, last != 0,
                             Wd + (size_t)bid * Tt * AD, AD,
                             den_meta, den_w, den_pbeg, den_padj,
                             den_init, den_final,
                             alpha_g + (size_t)bid * 1024, &res[bid], alpha, pk);
    } else {
        const int q = bid - 16;
        const int p = q >> 4, g = q & 15;
        const int s = g >> 3, b = g & 7;
        const int sp = p ? (1 - s) : s;
        const int L = seqlen[b * SS + sp];
        fsm_forward_tile<2>(NN, L, t0, Tt, first, last != 0,
                            Wn + (size_t)q * Tt * AN, AN,
                            num_meta + (size_t)g * AN, num_w + (size_t)g * AN,
                            num_pbeg + (size_t)g * (NN + 1), num_padj + (size_t)g * NN,
                            num_init + (size_t)g * NN, num_final + (size_t)g * NN,
                            alpha_g + (size_t)bid * 1024, &res[16 + q], alpha, pk);
    }
}

// res layout: [0..15] den (s*8+b), [16..31] num perm0, [32..47] num perm1
__global__ void finalize_kernel(const float* __restrict__ res, float* __restrict__ out)
{
    if (threadIdx.x == 0 && blockIdx.x == 0) {
        float loss = 0.f;
        for (int b = 0; b < BB; ++b) {
            const float den = res[b] + res[8 + b];
            const float n0  = res[16 + b] + res[16 + 8 + b];
            const float n1  = res[32 + b] + res[32 + 8 + b];
            const float nm  = fminf(n0, n1);
            loss += -(nm - den);
        }
        out[0] = loss;
    }
}

extern "C" void kernel_launch(void* const* d_in, const int* in_sizes, int n_in,
                              void* d_out, int out_size, void* d_ws, size_t ws_size,
                              hipStream_t stream)
{
    const float* est       = (const float*)d_in[0];
    const int*   seqlen    = (const int*)  d_in[1];
    const int*   den_src   = (const int*)  d_in[2];
    const int*   den_dst   = (const int*)  d_in[3];
    const int*   den_pdf   = (const int*)  d_in[4];
    const float* den_w     = (const float*)d_in[5];
    const float* den_init  = (const float*)d_in[6];
    const float* den_final = (const float*)d_in[7];
    const int*   num_src   = (const int*)  d_in[8];
    const int*   num_dst   = (const int*)  d_in[9];
    const int*   num_pdf   = (const int*)  d_in[10];
    const float* num_w     = (const float*)d_in[11];
    const float* num_init  = (const float*)d_in[12];
    const float* num_final = (const float*)d_in[13];

    char* ws = (char*)d_ws;
    unsigned* den_meta = (unsigned*)(ws + 0);        //  65536 -> 65536
    float*    den_wt   = (float*)   (ws + 65536);    //  65536 -> 131072
    unsigned* num_meta = (unsigned*)(ws + 131072);   // 131072 -> 262144
    float*    num_wt   = (float*)   (ws + 262144);   // 131072 -> 393216
    unsigned* den_pxi  = (unsigned*)(ws + 393216);   //  65536 -> 458752
    unsigned* num_pxi  = (unsigned*)(ws + 458752);   // 131072 -> 589824
    int*      den_pbeg = (int*)     (ws + 589824);   //   4100 -> 594176
    int*      num_pbeg = (int*)     (ws + 594176);   //  16448 -> 610816
    int*      den_padj = (int*)     (ws + 610816);   //   4096 -> 614912
    int*      num_padj = (int*)     (ws + 614912);   //  16384 -> 631296
    float*    alpha_g  = (float*)   (ws + 631296);   // 196608 -> 827904
    float*    res      = (float*)   (ws + 827904);   //    192 -> 828416
    const size_t fixed = 828416;

    // W double buffer: per buffer Tt*(16*AD + 32*AN)*4 = Tt*1310720 bytes
    int Tt = 64;
    while (Tt > 4 && fixed + 2ull * (size_t)Tt * 1310720ull > ws_size) Tt >>= 1;
    const size_t wbuf_f = (size_t)Tt * (16 * AD + 32 * AN);
    float* Wd0 = (float*)(ws + fixed);
    float* Wn0 = Wd0 + (size_t)16 * Tt * AD;
    float* Wd1 = Wd0 + wbuf_f;
    float* Wn1 = Wd1 + (size_t)16 * Tt * AD;

    // den: CH=16 (LC=4); num: CH=2 (LC=1)
    prep_kernel<<<1, 1024, 0, stream>>>(den_src, den_dst, den_pdf, den_w,
                                        den_meta, den_wt, den_pxi,
                                        den_pbeg, den_padj, ND, AD, 4);
    prep_kernel<<<16, 256, 0, stream>>>(num_src, num_dst, num_pdf, num_w,
                                        num_meta, num_wt, num_pxi,
                                        num_pbeg, num_padj, NN, AN, 1);

    wprep0_kernel<<<256, 1024, 0, stream>>>(est, den_pxi, num_pxi, Wd0, Wn0, 0, Tt);

    const int nt = TT / Tt;
    for (int k = 0; k < nt; ++k) {
        float* WdC = (k & 1) ? Wd1 : Wd0;
        float* WnC = (k & 1) ? Wn1 : Wn0;
        float* WdN = (k & 1) ? Wd0 : Wd1;
        float* WnN = (k & 1) ? Wn0 : Wn1;
        fused_kernel<<<NWG, 1024, 0, stream>>>(seqlen, WdC, WnC,
                                               den_meta, den_wt, den_pbeg, den_padj,
                                               den_init, den_final,
                                               num_meta, num_wt, num_pbeg, num_padj,
                                               num_init, num_final,
                                               alpha_g, res, k * Tt, Tt,
                                               (k == nt - 1) ? 1 : 0,
                                               est, den_pxi, num_pxi, WdN, WnN);
    }

    finalize_kernel<<<1, 64, 0, stream>>>(res, (float*)d_out);
}